// Round 1
// 232.673 us; speedup vs baseline: 1.0408x; 1.0408x over previous
//
#include <hip/hip_runtime.h>
#include <stdint.h>

typedef __attribute__((ext_vector_type(8))) short short8;
typedef __attribute__((ext_vector_type(4))) float f32x4;

// ---- byte offsets into d_ws (total 74,054,656 B; proven ws >= 75.7 MB in R1-R3) ----
#define B_BNA    0ull          // 24*625 fp32            = 60000  -> pad 60416
#define B_STATS  60416ull      // 4*256 fp32             = 4096
#define B_RESW2  64512ull      // 256*128 bf16           = 65536
#define B_PART   130048ull     // (unused now)
#define B_E2     1178624ull    // 8*8*13*128*32 bf16     = 6815744
#define B_XB     7994368ull    // 2048*3328 bf16         = 13631488
#define B_MAIN   21625856ull   // 2048*256*25 bf16       = 26214400
#define B_RES    47840256ull   // 2048*256*25 bf16       = 26214400  (end 74054656)

#define NTV 51200.0f

__device__ __forceinline__ unsigned short f2bf(float f) {
    unsigned u = __float_as_uint(f);
    return (unsigned short)((u + 0x7fffu + ((u >> 16) & 1u)) >> 16);
}
__device__ __forceinline__ float bf2f(unsigned s) { return __uint_as_float(s << 16); }

__device__ __forceinline__ float wave_sum(float v) {
#pragma unroll
    for (int m = 1; m < 64; m <<= 1) v += __shfl_xor(v, m, 64);
    return v;
}

// async global->LDS, 16B per lane; HW dest = wave-uniform base + lane*16
__device__ __forceinline__ void gl_lds16(const unsigned short* g, unsigned short* l) {
    __builtin_amdgcn_global_load_lds(
        (const __attribute__((address_space(1))) unsigned int*)g,
        (__attribute__((address_space(3))) unsigned int*)l, 16, 0, 0);
}

// K1: BnA (fp32), zero stats, res_w -> bf16 copy
__global__ __launch_bounds__(256) void k_prep(const int* __restrict__ hop,
                                              const float* __restrict__ emb,
                                              const float* __restrict__ A,
                                              const float* __restrict__ res_w,
                                              float* __restrict__ bna,
                                              float* __restrict__ stats,
                                              unsigned short* __restrict__ resw2) {
    int g = blockIdx.x, tid = threadIdx.x;
    if (g < 24) {
        if (tid < 25) {
            int w = tid;
            float nb = 0.f, na = 0.f;
            for (int v = 0; v < 25; v++) {
                float e = emb[g*12 + hop[v*25 + w]];
                nb += e*e;
                float a = A[((size_t)g*25 + v)*25 + w];
                na += a*a;
            }
            nb = sqrtf(nb) + 1e-4f;
            na = sqrtf(na) + 1e-4f;
            for (int v = 0; v < 25; v++) {
                float e = emb[g*12 + hop[v*25 + w]];
                float a = A[((size_t)g*25 + v)*25 + w];
                bna[g*625 + v*25 + w] = e/nb + a/na;
            }
        }
    } else if (g == 24) {
#pragma unroll
        for (int i = 0; i < 4; i++) stats[i*256 + tid] = 0.f;
    } else {
        int base = (g - 25) * 4096 + tid * 16;
#pragma unroll
        for (int j = 0; j < 16; j++) resw2[base + j] = f2bf(res_w[base + j]);
    }
}

// K2+K3 merged (independent work; prep2 alone underfills 256 CUs at 128 blocks).
// blocks [0,128): E2 build.  blocks [128,2176): x -> xb bf16 repack.
__global__ __launch_bounds__(256) void k_prep2x(const float* __restrict__ w_block,
                                                const float* __restrict__ bna,
                                                unsigned short* __restrict__ E2,
                                                const float* __restrict__ x,
                                                unsigned short* __restrict__ xb) {
    int bid = blockIdx.x, tid = threadIdx.x;
    if (bid < 128) {
        __shared__ float bl[3*625];
        __shared__ float wl[3*64];
        int half = bid & 1, og = (bid >> 1) & 7, h = bid >> 4;

        for (int i = tid; i < 1875; i += 256) {
            int k3 = i / 625, j = i - k3*625;
            bl[i] = bna[(k3*8 + h)*625 + j];
        }
        if (tid < 192) {
            int k3 = tid >> 6, o = (tid >> 4) & 3, c = tid & 15;
            wl[tid] = w_block[(k3*256 + h*32 + og*4 + o)*16 + c];
        }
        __syncthreads();

        unsigned short* dst = E2 + (size_t)(h*8 + og)*53248;
        int e0 = half * 26624;
        for (int e = e0 + tid; e < e0 + 26624; e += 256) {
            int kc = e >> 12;
            int n  = (e >> 5) & 127;
            int kk = e & 31;
            int k  = kc*32 + kk;
            int o  = n >> 5, w = n & 31;
            float val = 0.f;
            if (k < 400 && w < 25) {
                int c = k / 25, v = k - c*25;
                val = wl[0*64 + o*16 + c] * bl[0*625 + v*25 + w]
                    + wl[1*64 + o*16 + c] * bl[1*625 + v*25 + w]
                    + wl[2*64 + o*16 + c] * bl[2*625 + v*25 + w];
            }
            dst[e] = f2bf(val);
        }
    } else {
        int b = bid - 128;
        int n_ = b >> 7, t_ = b & 127;
        unsigned short* row = xb + (size_t)b * 3328;
        for (int idx = tid; idx < 3200; idx += 256) {
            int c = idx / 25, v = idx - c*25;
            float val = x[(((size_t)n_*128 + c)*128 + t_)*25 + v];
            row[(c >> 4)*416 + (c & 15)*25 + v] = f2bf(val);
        }
        if (tid < 128) row[(tid >> 4)*416 + 400 + (tid & 15)] = 0;
    }
}

// K4+K5 merged: blocks [0,1024) = main GEMM (gc), blocks [1024,1824) = residual GEMM.
// gc decode XCD-swizzled: h = bid&7 so all blocks sharing an xb h-slice / E2 chunk
// land on one XCD (per-XCD working set ~2.5 MB < 4 MB L2).
// gc staging via global_load_lds width=16 (no VGPR round-trip).
__global__ __launch_bounds__(256) void k_mm(const unsigned short* __restrict__ xb,
                                            const unsigned short* __restrict__ E2,
                                            unsigned short* __restrict__ mainp,
                                            const float* __restrict__ x,
                                            const unsigned short* __restrict__ resw2,
                                            unsigned short* __restrict__ resp,
                                            float* __restrict__ stats) {
    __shared__ unsigned short Alds[128*32];
    __shared__ unsigned short Blds[128*32];
    int bid = blockIdx.x, tid = threadIdx.x;
    int lane = tid & 63, wave = tid >> 6;
    int wm = wave >> 1, wn = wave & 1;
    int lane15 = lane & 15, quad = lane >> 4;

    if (bid < 1024) {
        // h fastest -> bid%8==h -> same-h blocks share an XCD L2
        int h = bid & 7, og = (bid >> 3) & 7, mt = bid >> 6;

        // per-lane 16B chunk: row = wave*32 + q*16 + (lane>>2), col16 = lane&3
        const unsigned short* ag = xb + (size_t)(mt*128 + wave*32 + (lane>>2))*3328
                                      + h*416 + (lane&3)*8;
        const unsigned short* bg = E2 + (size_t)(h*8 + og)*53248 + wave*1024 + lane*8;
        unsigned short* al = &Alds[wave*1024 + lane*8];
        unsigned short* bl = &Blds[wave*1024 + lane*8];

        f32x4 acc[4][4] = {};

        for (int kc = 0; kc < 13; kc++) {
            gl_lds16(ag,          al);        // rows wave*32 +  0..15
            gl_lds16(ag + 53248,  al + 512);  // rows wave*32 + 16..31 (16*3328)
            gl_lds16(bg,          bl);
            gl_lds16(bg + 512,    bl + 512);
            ag += 32; bg += 4096;
            __syncthreads();   // drains vmcnt (global_load_lds) before ds_read

            short8 af[4], bf[4];
#pragma unroll
            for (int i = 0; i < 4; i++) {
                af[i] = *(const short8*)&Alds[(wm*64 + i*16 + lane15)*32 + quad*8];
                bf[i] = *(const short8*)&Blds[(wn*64 + i*16 + lane15)*32 + quad*8];
            }
#pragma unroll
            for (int i = 0; i < 4; i++)
#pragma unroll
                for (int j = 0; j < 4; j++)
                    acc[i][j] = __builtin_amdgcn_mfma_f32_16x16x32_bf16(af[i], bf[j], acc[i][j], 0, 0, 0);
            __syncthreads();
        }

        // epilogue: n = wn*64 + j*16 + lane15 = o*32 + w
        float s1[2] = {0.f, 0.f}, s2[2] = {0.f, 0.f};
#pragma unroll
        for (int j = 0; j < 4; j++) {
            int w = (j & 1)*16 + lane15;
            int p = j >> 1;
            if (w < 25) {
                int oc = h*32 + og*4 + wn*2 + p;
#pragma unroll
                for (int i = 0; i < 4; i++) {
                    int mb = mt*128 + wm*64 + i*16 + quad*4;
#pragma unroll
                    for (int r = 0; r < 4; r++) {
                        float val = acc[i][j][r];
                        mainp[(size_t)((mb + r)*256 + oc)*25 + w] = f2bf(val);
                        s1[p] += val;
                        s2[p] = fmaf(val, val, s2[p]);
                    }
                }
            }
        }
#pragma unroll
        for (int p = 0; p < 2; p++) {
            float a = wave_sum(s1[p]);
            float b = wave_sum(s2[p]);
            if (lane == 0) {
                int oc = h*32 + og*4 + wn*2 + p;
                atomicAdd(&stats[oc], a);
                atomicAdd(&stats[256 + oc], b);
            }
        }
    } else {
        // residual GEMM: pair (mt, nt=0/1) at bids b2 and b2+400 -> same XCD (400%8==0)
        int b2 = bid - 1024;
        int nt = (b2 >= 400) ? 1 : 0;
        int mt = b2 - nt*400;

        int m2row = tid >> 1, shalf = tid & 1;
        int m2 = mt*128 + m2row;
        int bb = m2 / 25, vv = m2 - bb*25;
        int n_ = bb >> 7, t_ = bb & 127;
        const float* xbase = x + ((size_t)n_*128*128 + t_)*25 + vv;  // + c*3200

        const unsigned short* rbg = resw2 + (size_t)(nt*128 + wave*32 + (lane>>2))*128
                                          + (lane&3)*8;
        unsigned short* bl = &Blds[wave*1024 + lane*8];

        f32x4 acc[4][4] = {};

        for (int kc = 0; kc < 4; kc++) {
            {
                unsigned short tmp[16];
                int c0 = kc*32 + shalf*16;
#pragma unroll
                for (int j = 0; j < 16; j++)
                    tmp[j] = f2bf(xbase[(size_t)(c0 + j)*3200]);
                unsigned pk[8];
#pragma unroll
                for (int q = 0; q < 8; q++)
                    pk[q] = (unsigned)tmp[2*q] | ((unsigned)tmp[2*q+1] << 16);
                *(uint4*)&Alds[m2row*32 + shalf*16]     = make_uint4(pk[0], pk[1], pk[2], pk[3]);
                *(uint4*)&Alds[m2row*32 + shalf*16 + 8] = make_uint4(pk[4], pk[5], pk[6], pk[7]);
            }
            gl_lds16(rbg + kc*32,        bl);        // rows wave*32 +  0..15
            gl_lds16(rbg + 2048 + kc*32, bl + 512);  // rows wave*32 + 16..31 (16*128)
            __syncthreads();

            short8 af[4], bf[4];
#pragma unroll
            for (int i = 0; i < 4; i++) {
                af[i] = *(const short8*)&Alds[(wm*64 + i*16 + lane15)*32 + quad*8];
                bf[i] = *(const short8*)&Blds[(wn*64 + i*16 + lane15)*32 + quad*8];
            }
#pragma unroll
            for (int i = 0; i < 4; i++)
#pragma unroll
                for (int j = 0; j < 4; j++)
                    acc[i][j] = __builtin_amdgcn_mfma_f32_16x16x32_bf16(af[i], bf[j], acc[i][j], 0, 0, 0);
            __syncthreads();
        }

#pragma unroll
        for (int j = 0; j < 4; j++) {
            int oc = nt*128 + wn*64 + j*16 + lane15;
            float s1 = 0.f, s2 = 0.f;
#pragma unroll
            for (int i = 0; i < 4; i++) {
                int m2b = mt*128 + wm*64 + i*16 + quad*4;
#pragma unroll
                for (int r = 0; r < 4; r++) {
                    float val = acc[i][j][r];
                    int m2e = m2b + r;
                    int b = m2e / 25, v = m2e - b*25;
                    resp[(size_t)(b*256 + oc)*25 + v] = f2bf(val);
                    s1 += val;
                    s2 = fmaf(val, val, s2);
                }
            }
            s1 += __shfl_xor(s1, 16, 64); s1 += __shfl_xor(s1, 32, 64);
            s2 += __shfl_xor(s2, 16, 64); s2 += __shfl_xor(s2, 32, 64);
            if (quad == 0) {
                atomicAdd(&stats[512 + oc], s1);
                atomicAdd(&stats[768 + oc], s2);
            }
        }
    }
}

// K6: out = relu(BN1(main) + BN2(res))
__global__ __launch_bounds__(256) void k_final(const float* __restrict__ bn_g,
                                               const float* __restrict__ bn_b,
                                               const float* __restrict__ rbn_g,
                                               const float* __restrict__ rbn_b,
                                               const float* __restrict__ stats,
                                               const unsigned short* __restrict__ mainp,
                                               const unsigned short* __restrict__ resp,
                                               float* __restrict__ out) {
    int b = blockIdx.x;
    int n_ = b >> 7, t_ = b & 127;
    int oc = threadIdx.x;
    const float inv = 1.f / NTV;
    float s1 = stats[oc],       s2 = stats[256 + oc];
    float r1 = stats[512 + oc], r2 = stats[768 + oc];
    float mm = s1*inv, vm = s2*inv - mm*mm;
    float mr = r1*inv, vr = r2*inv - mr*mr;
    float a1 = bn_g[oc]  * rsqrtf(vm + 1e-5f); float c1 = bn_b[oc]  - a1*mm;
    float a2 = rbn_g[oc] * rsqrtf(vr + 1e-5f); float c2 = rbn_b[oc] - a2*mr;

    const unsigned short* mrow = mainp + (size_t)(b*256 + oc)*25;
    const unsigned short* rrow = resp  + (size_t)(b*256 + oc)*25;
    float* op = out + ((size_t)(n_*256 + oc)*128 + t_)*25;
#pragma unroll
    for (int w = 0; w < 25; w++) {
        float val = fmaf(a1, bf2f(mrow[w]), c1) + fmaf(a2, bf2f(rrow[w]), c2);
        op[w] = fmaxf(val, 0.f);
    }
}

extern "C" void kernel_launch(void* const* d_in, const int* in_sizes, int n_in,
                              void* d_out, int out_size, void* d_ws, size_t ws_size,
                              hipStream_t stream) {
    const float* x        = (const float*)d_in[0];
    const int*   hop      = (const int*)  d_in[1];
    const float* emb      = (const float*)d_in[2];
    const float* A        = (const float*)d_in[3];
    const float* w_block  = (const float*)d_in[4];
    // d_in[5] b_block, d_in[9] res_b: per-channel biases cancel under batchnorm.
    const float* bn_g     = (const float*)d_in[6];
    const float* bn_b     = (const float*)d_in[7];
    const float* res_w    = (const float*)d_in[8];
    const float* rbn_g    = (const float*)d_in[10];
    const float* rbn_b    = (const float*)d_in[11];
    float* out = (float*)d_out;

    char* ws = (char*)d_ws;
    float*          bna    = (float*)(ws + B_BNA);
    float*          stats  = (float*)(ws + B_STATS);
    unsigned short* resw2  = (unsigned short*)(ws + B_RESW2);
    unsigned short* E2     = (unsigned short*)(ws + B_E2);
    unsigned short* xb     = (unsigned short*)(ws + B_XB);
    unsigned short* mainp  = (unsigned short*)(ws + B_MAIN);
    unsigned short* resp   = (unsigned short*)(ws + B_RES);

    k_prep   <<<33,   256, 0, stream>>>(hop, emb, A, res_w, bna, stats, resw2);
    k_prep2x <<<2176, 256, 0, stream>>>(w_block, bna, E2, x, xb);
    k_mm     <<<1824, 256, 0, stream>>>(xb, E2, mainp, x, resw2, resp, stats);
    k_final  <<<2048, 256, 0, stream>>>(bn_g, bn_b, rbn_g, rbn_b, stats, mainp, resp, out);
}

// Round 2
// 222.545 us; speedup vs baseline: 1.0881x; 1.0455x over previous
//
#include <hip/hip_runtime.h>
#include <stdint.h>

typedef __attribute__((ext_vector_type(8))) short short8;
typedef __attribute__((ext_vector_type(4))) float f32x4;

// ---- byte offsets into d_ws (total 74,054,656 B; proven ws >= 75.7 MB in R1-R3) ----
#define B_BNA    0ull          // 24*625 fp32            = 60000  -> pad 60416
#define B_STATS  60416ull      // 4*256 fp32             = 4096
#define B_RESW2  64512ull      // 256*128 bf16           = 65536
#define B_E2     1178624ull    // 8*8*13*128*32 bf16     = 6815744
#define B_XB     7994368ull    // 2048*3328 bf16         = 13631488
#define B_MAIN   21625856ull   // 2048*256*25 bf16       = 26214400
#define B_RES    47840256ull   // 2048*256*25 bf16       = 26214400  (end 74054656)

#define NTV 51200.0f

__device__ __forceinline__ unsigned short f2bf(float f) {
    unsigned u = __float_as_uint(f);
    return (unsigned short)((u + 0x7fffu + ((u >> 16) & 1u)) >> 16);
}
__device__ __forceinline__ float bf2f(unsigned s) { return __uint_as_float(s << 16); }

__device__ __forceinline__ float wave_sum(float v) {
#pragma unroll
    for (int m = 1; m < 64; m <<= 1) v += __shfl_xor(v, m, 64);
    return v;
}

// async global->LDS, 16B per lane; HW dest = wave-uniform base + lane*16
__device__ __forceinline__ void gl_lds16(const unsigned short* g, unsigned short* l) {
    __builtin_amdgcn_global_load_lds(
        (const __attribute__((address_space(1))) unsigned int*)g,
        (__attribute__((address_space(3))) unsigned int*)l, 16, 0, 0);
}
__device__ __forceinline__ void stage_pair(const unsigned short* g0, const unsigned short* g1,
                                           unsigned short* d) {
    gl_lds16(g0, d);
    gl_lds16(g1, d + 512);
}

// LDS tile swizzle: data (row, quad-of-16B) stored at byte (row*64 + quad*16) ^ ((row&7)<<4).
// Bijective (bit6 flip pairs rows r / r^1). Read phases: 2 lanes/bank-group = conflict-free.
// Short-index form:
__device__ __forceinline__ int swz_idx(int row, int quad) {
    int rowX = row ^ ((row >> 2) & 1);
    return rowX * 32 + ((quad ^ (row & 3)) << 3);
}

// K1: BnA (fp32), zero stats, res_w -> bf16 copy
__global__ __launch_bounds__(256) void k_prep(const int* __restrict__ hop,
                                              const float* __restrict__ emb,
                                              const float* __restrict__ A,
                                              const float* __restrict__ res_w,
                                              float* __restrict__ bna,
                                              float* __restrict__ stats,
                                              unsigned short* __restrict__ resw2) {
    int g = blockIdx.x, tid = threadIdx.x;
    if (g < 24) {
        if (tid < 25) {
            int w = tid;
            float nb = 0.f, na = 0.f;
            for (int v = 0; v < 25; v++) {
                float e = emb[g*12 + hop[v*25 + w]];
                nb += e*e;
                float a = A[((size_t)g*25 + v)*25 + w];
                na += a*a;
            }
            nb = sqrtf(nb) + 1e-4f;
            na = sqrtf(na) + 1e-4f;
            for (int v = 0; v < 25; v++) {
                float e = emb[g*12 + hop[v*25 + w]];
                float a = A[((size_t)g*25 + v)*25 + w];
                bna[g*625 + v*25 + w] = e/nb + a/na;
            }
        }
    } else if (g == 24) {
#pragma unroll
        for (int i = 0; i < 4; i++) stats[i*256 + tid] = 0.f;
    } else {
        int base = (g - 25) * 4096 + tid * 16;
#pragma unroll
        for (int j = 0; j < 16; j++) resw2[base + j] = f2bf(res_w[base + j]);
    }
}

// K2+K3 merged. blocks [0,128): E2 build.  blocks [128,2176): x -> xb bf16 repack.
__global__ __launch_bounds__(256) void k_prep2x(const float* __restrict__ w_block,
                                                const float* __restrict__ bna,
                                                unsigned short* __restrict__ E2,
                                                const float* __restrict__ x,
                                                unsigned short* __restrict__ xb) {
    int bid = blockIdx.x, tid = threadIdx.x;
    if (bid < 128) {
        __shared__ float bl[3*625];
        __shared__ float wl[3*64];
        int half = bid & 1, og = (bid >> 1) & 7, h = bid >> 4;

        for (int i = tid; i < 1875; i += 256) {
            int k3 = i / 625, j = i - k3*625;
            bl[i] = bna[(k3*8 + h)*625 + j];
        }
        if (tid < 192) {
            int k3 = tid >> 6, o = (tid >> 4) & 3, c = tid & 15;
            wl[tid] = w_block[(k3*256 + h*32 + og*4 + o)*16 + c];
        }
        __syncthreads();

        unsigned short* dst = E2 + (size_t)(h*8 + og)*53248;
        int e0 = half * 26624;
        for (int e = e0 + tid; e < e0 + 26624; e += 256) {
            int kc = e >> 12;
            int n  = (e >> 5) & 127;
            int kk = e & 31;
            int k  = kc*32 + kk;
            int o  = n >> 5, w = n & 31;
            float val = 0.f;
            if (k < 400 && w < 25) {
                int c = k / 25, v = k - c*25;
                val = wl[0*64 + o*16 + c] * bl[0*625 + v*25 + w]
                    + wl[1*64 + o*16 + c] * bl[1*625 + v*25 + w]
                    + wl[2*64 + o*16 + c] * bl[2*625 + v*25 + w];
            }
            dst[e] = f2bf(val);
        }
    } else {
        int b = bid - 128;
        int n_ = b >> 7, t_ = b & 127;
        unsigned short* row = xb + (size_t)b * 3328;
        for (int idx = tid; idx < 3200; idx += 256) {
            int c = idx / 25, v = idx - c*25;
            float val = x[(((size_t)n_*128 + c)*128 + t_)*25 + v];
            row[(c >> 4)*416 + (c & 15)*25 + v] = f2bf(val);
        }
        if (tid < 128) row[(tid >> 4)*416 + 400 + (tid & 15)] = 0;
    }
}

// K4+K5 merged: blocks [0,1024) = main GEMM (gc, XCD-pinned h=bid&7, gl_lds + dbuf,
// swizzled LDS), blocks [1024,1824) = residual GEMM (coalesced x staging).
__global__ __launch_bounds__(256) void k_mm(const unsigned short* __restrict__ xb,
                                            const unsigned short* __restrict__ E2,
                                            unsigned short* __restrict__ mainp,
                                            const float* __restrict__ x,
                                            const unsigned short* __restrict__ resw2,
                                            unsigned short* __restrict__ resp,
                                            float* __restrict__ stats) {
    // [0..4095]=A0 [4096..8191]=B0 [8192..12287]=A1 [12288..16383]=B1 (shorts)
    __shared__ unsigned short lds[16384];
    int bid = blockIdx.x, tid = threadIdx.x;
    int lane = tid & 63, wave = tid >> 6;
    int wm = wave >> 1, wn = wave & 1;
    int lane15 = lane & 15, quad = lane >> 4;

    // inverse swizzle for linear gl_lds destinations (loop-invariant):
    // storage slot (Lrow, Lq) holds data (r = Lrow ^ ((Lrow>>2)&1), q = Lq ^ (r&3))
    int Lrow0 = wave*32 + (lane >> 2), Lq = lane & 3;
    int r0 = Lrow0 ^ ((Lrow0 >> 2) & 1), q0 = Lq ^ (r0 & 3);
    int Lrow1 = Lrow0 + 16;
    int r1 = Lrow1 ^ ((Lrow1 >> 2) & 1), q1 = Lq ^ (r1 & 3);

    unsigned short* Ad = lds        + wave*1024 + lane*8;   // dest in A-buf0
    unsigned short* Bd = lds + 4096 + wave*1024 + lane*8;   // dest in B-buf0

    if (bid < 1024) {
        // h fastest -> bid%8==h -> same-h blocks share an XCD L2
        int h = bid & 7, og = (bid >> 3) & 7, mt = bid >> 6;

        const unsigned short* agA0 = xb + (size_t)(mt*128 + r0)*3328 + h*416 + q0*8;
        const unsigned short* agA1 = xb + (size_t)(mt*128 + r1)*3328 + h*416 + q1*8;
        const unsigned short* eb   = E2 + (size_t)(h*8 + og)*53248;
        const unsigned short* bgB0 = eb + r0*32 + q0*8;
        const unsigned short* bgB1 = eb + r1*32 + q1*8;

        f32x4 acc[4][4] = {};

        // prologue: stage kc=0 into buf0
        stage_pair(agA0, agA1, Ad);
        stage_pair(bgB0, bgB1, Bd);
        __syncthreads();

        for (int kc = 0; kc < 13; kc++) {
            int cur = (kc & 1) << 13;            // 0 or 8192
            if (kc < 12) {
                int nxt = 8192 - cur;
                stage_pair(agA0 + (kc+1)*32,            agA1 + (kc+1)*32,            Ad + nxt);
                stage_pair(bgB0 + (size_t)(kc+1)*4096,  bgB1 + (size_t)(kc+1)*4096,  Bd + nxt);
                __builtin_amdgcn_sched_barrier(0);   // keep stage issue ahead of compute
            }
            const unsigned short* Ac = lds + cur;
            const unsigned short* Bc = lds + 4096 + cur;

            short8 af[4], bq[4];
#pragma unroll
            for (int i = 0; i < 4; i++) {
                af[i] = *(const short8*)&Ac[swz_idx(wm*64 + i*16 + lane15, quad)];
                bq[i] = *(const short8*)&Bc[swz_idx(wn*64 + i*16 + lane15, quad)];
            }
#pragma unroll
            for (int i = 0; i < 4; i++)
#pragma unroll
                for (int j = 0; j < 4; j++)
                    acc[i][j] = __builtin_amdgcn_mfma_f32_16x16x32_bf16(af[i], bq[j], acc[i][j], 0, 0, 0);
            if (kc < 12) __syncthreads();        // drains this iter's stage (post-MFMA: cheap)
        }

        // epilogue: n = wn*64 + j*16 + lane15 = o*32 + w
        float s1[2] = {0.f, 0.f}, s2[2] = {0.f, 0.f};
#pragma unroll
        for (int j = 0; j < 4; j++) {
            int w = (j & 1)*16 + lane15;
            int p = j >> 1;
            if (w < 25) {
                int oc = h*32 + og*4 + wn*2 + p;
#pragma unroll
                for (int i = 0; i < 4; i++) {
                    int mb = mt*128 + wm*64 + i*16 + quad*4;
#pragma unroll
                    for (int r = 0; r < 4; r++) {
                        float val = acc[i][j][r];
                        mainp[(size_t)((mb + r)*256 + oc)*25 + w] = f2bf(val);
                        s1[p] += val;
                        s2[p] = fmaf(val, val, s2[p]);
                    }
                }
            }
        }
#pragma unroll
        for (int p = 0; p < 2; p++) {
            float a = wave_sum(s1[p]);
            float b = wave_sum(s2[p]);
            if (lane == 0) {
                int oc = h*32 + og*4 + wn*2 + p;
                atomicAdd(&stats[oc], a);
                atomicAdd(&stats[256 + oc], b);
            }
        }
    } else {
        // residual GEMM: pair (mt, nt=0/1) at bids b2, b2+400 -> same XCD (400%8==0)
        int b2 = bid - 1024;
        int nt = (b2 >= 400) ? 1 : 0;
        int mt = b2 - nt*400;

        // m2 = n*3200 + t*25 + v; tile of 128 m2 never straddles n (3200%128==0).
        // x addr = n*409600 + c*3200 + (m2 - n*3200): contiguous in m2 for fixed (n,c).
        int n  = mt / 25;
        int off = (mt - n*25) * 128;
        const float* xb2 = x + (size_t)n*409600 + off;

        int c2 = tid >> 4, seg = tid & 15;   // c-pair (2c2,2c2+1), m = seg + 16j

        const unsigned short* rb0 = resw2 + (size_t)(nt*128 + r0)*128 + q0*8;
        const unsigned short* rb1 = resw2 + (size_t)(nt*128 + r1)*128 + q1*8;

        f32x4 acc[4][4] = {};

        for (int kc = 0; kc < 4; kc++) {
            // B stage first (latency overlaps the A pack below)
            stage_pair(rb0 + kc*32, rb1 + kc*32, Bd);
            // A: coalesced fp32 loads (16 lanes same c -> 64B lines), swizzled packed writes
            const float* xc0 = xb2 + (size_t)(kc*32 + 2*c2)*3200;
            const float* xc1 = xc0 + 3200;
            int wbase = 2*(c2 & 3), qn = c2 >> 2;
#pragma unroll
            for (int j = 0; j < 8; j++) {
                int m = seg + 16*j;
                unsigned pk = (unsigned)f2bf(xc0[m]) | ((unsigned)f2bf(xc1[m]) << 16);
                *(unsigned*)&lds[swz_idx(m, qn) + wbase] = pk;
            }
            __syncthreads();

            short8 af[4], bq[4];
#pragma unroll
            for (int i = 0; i < 4; i++) {
                af[i] = *(const short8*)&lds[swz_idx(wm*64 + i*16 + lane15, quad)];
                bq[i] = *(const short8*)&lds[4096 + swz_idx(wn*64 + i*16 + lane15, quad)];
            }
#pragma unroll
            for (int i = 0; i < 4; i++)
#pragma unroll
                for (int j = 0; j < 4; j++)
                    acc[i][j] = __builtin_amdgcn_mfma_f32_16x16x32_bf16(af[i], bq[j], acc[i][j], 0, 0, 0);
            __syncthreads();
        }

#pragma unroll
        for (int j = 0; j < 4; j++) {
            int oc = nt*128 + wn*64 + j*16 + lane15;
            float s1 = 0.f, s2 = 0.f;
#pragma unroll
            for (int i = 0; i < 4; i++) {
                int m2b = mt*128 + wm*64 + i*16 + quad*4;
#pragma unroll
                for (int r = 0; r < 4; r++) {
                    float val = acc[i][j][r];
                    int m2e = m2b + r;
                    int b = m2e / 25, v = m2e - b*25;
                    resp[(size_t)(b*256 + oc)*25 + v] = f2bf(val);
                    s1 += val;
                    s2 = fmaf(val, val, s2);
                }
            }
            s1 += __shfl_xor(s1, 16, 64); s1 += __shfl_xor(s1, 32, 64);
            s2 += __shfl_xor(s2, 16, 64); s2 += __shfl_xor(s2, 32, 64);
            if (quad == 0) {
                atomicAdd(&stats[512 + oc], s1);
                atomicAdd(&stats[768 + oc], s2);
            }
        }
    }
}

// K6: out = relu(BN1(main) + BN2(res))
__global__ __launch_bounds__(256) void k_final(const float* __restrict__ bn_g,
                                               const float* __restrict__ bn_b,
                                               const float* __restrict__ rbn_g,
                                               const float* __restrict__ rbn_b,
                                               const float* __restrict__ stats,
                                               const unsigned short* __restrict__ mainp,
                                               const unsigned short* __restrict__ resp,
                                               float* __restrict__ out) {
    int b = blockIdx.x;
    int n_ = b >> 7, t_ = b & 127;
    int oc = threadIdx.x;
    const float inv = 1.f / NTV;
    float s1 = stats[oc],       s2 = stats[256 + oc];
    float r1 = stats[512 + oc], r2 = stats[768 + oc];
    float mm = s1*inv, vm = s2*inv - mm*mm;
    float mr = r1*inv, vr = r2*inv - mr*mr;
    float a1 = bn_g[oc]  * rsqrtf(vm + 1e-5f); float c1 = bn_b[oc]  - a1*mm;
    float a2 = rbn_g[oc] * rsqrtf(vr + 1e-5f); float c2 = rbn_b[oc] - a2*mr;

    const unsigned short* mrow = mainp + (size_t)(b*256 + oc)*25;
    const unsigned short* rrow = resp  + (size_t)(b*256 + oc)*25;
    float* op = out + ((size_t)(n_*256 + oc)*128 + t_)*25;
#pragma unroll
    for (int w = 0; w < 25; w++) {
        float val = fmaf(a1, bf2f(mrow[w]), c1) + fmaf(a2, bf2f(rrow[w]), c2);
        op[w] = fmaxf(val, 0.f);
    }
}

extern "C" void kernel_launch(void* const* d_in, const int* in_sizes, int n_in,
                              void* d_out, int out_size, void* d_ws, size_t ws_size,
                              hipStream_t stream) {
    const float* x        = (const float*)d_in[0];
    const int*   hop      = (const int*)  d_in[1];
    const float* emb      = (const float*)d_in[2];
    const float* A        = (const float*)d_in[3];
    const float* w_block  = (const float*)d_in[4];
    // d_in[5] b_block, d_in[9] res_b: per-channel biases cancel under batchnorm.
    const float* bn_g     = (const float*)d_in[6];
    const float* bn_b     = (const float*)d_in[7];
    const float* res_w    = (const float*)d_in[8];
    const float* rbn_g    = (const float*)d_in[10];
    const float* rbn_b    = (const float*)d_in[11];
    float* out = (float*)d_out;

    char* ws = (char*)d_ws;
    float*          bna    = (float*)(ws + B_BNA);
    float*          stats  = (float*)(ws + B_STATS);
    unsigned short* resw2  = (unsigned short*)(ws + B_RESW2);
    unsigned short* E2     = (unsigned short*)(ws + B_E2);
    unsigned short* xb     = (unsigned short*)(ws + B_XB);
    unsigned short* mainp  = (unsigned short*)(ws + B_MAIN);
    unsigned short* resp   = (unsigned short*)(ws + B_RES);

    k_prep   <<<33,   256, 0, stream>>>(hop, emb, A, res_w, bna, stats, resw2);
    k_prep2x <<<2176, 256, 0, stream>>>(w_block, bna, E2, x, xb);
    k_mm     <<<1824, 256, 0, stream>>>(xb, E2, mainp, x, resw2, resp, stats);
    k_final  <<<2048, 256, 0, stream>>>(bn_g, bn_b, rbn_g, rbn_b, stats, mainp, resp, out);
}

// Round 3
// 206.318 us; speedup vs baseline: 1.1737x; 1.0787x over previous
//
#include <hip/hip_runtime.h>
#include <stdint.h>

typedef __attribute__((ext_vector_type(8))) short short8;
typedef __attribute__((ext_vector_type(4))) float f32x4;

// ---- byte offsets into d_ws (total 74,054,656 B; proven ws >= 75.7 MB in R1-R3) ----
#define B_BNA    0ull          // 24*625 fp32            = 60000  -> pad 60416
#define B_STATS  60416ull      // 4*256 fp32             = 4096
#define B_RESW2  64512ull      // 256*128 bf16           = 65536
#define B_E2     1178624ull    // 8*8*13*128*32 bf16     = 6815744
#define B_XB     7994368ull    // 2048*3328 bf16         = 13631488
#define B_MAIN   21625856ull   // 16*256*128*25 bf16     = 26214400  (layout = out)
#define B_RES    47840256ull   // 16*256*128*25 bf16     = 26214400  (end 74054656)

#define NTV 51200.0f

__device__ __forceinline__ unsigned short f2bf(float f) {
    unsigned u = __float_as_uint(f);
    return (unsigned short)((u + 0x7fffu + ((u >> 16) & 1u)) >> 16);
}
__device__ __forceinline__ float bf2f(unsigned s) { return __uint_as_float(s << 16); }

__device__ __forceinline__ float wave_sum(float v) {
#pragma unroll
    for (int m = 1; m < 64; m <<= 1) v += __shfl_xor(v, m, 64);
    return v;
}

// async global->LDS, 16B per lane; HW dest = wave-uniform base + lane*16
__device__ __forceinline__ void gl_lds16(const unsigned short* g, unsigned short* l) {
    __builtin_amdgcn_global_load_lds(
        (const __attribute__((address_space(1))) unsigned int*)g,
        (__attribute__((address_space(3))) unsigned int*)l, 16, 0, 0);
}
__device__ __forceinline__ void stage_pair(const unsigned short* g0, const unsigned short* g1,
                                           unsigned short* d) {
    gl_lds16(g0, d);
    gl_lds16(g1, d + 512);
}

// LDS tile swizzle (kept from R2; harmless, write-side pre-swizzled).
__device__ __forceinline__ int swz_idx(int row, int quad) {
    int rowX = row ^ ((row >> 2) & 1);
    return rowX * 32 + ((quad ^ (row & 3)) << 3);
}

// K1: BnA (fp32), zero stats, res_w -> bf16 copy
__global__ __launch_bounds__(256) void k_prep(const int* __restrict__ hop,
                                              const float* __restrict__ emb,
                                              const float* __restrict__ A,
                                              const float* __restrict__ res_w,
                                              float* __restrict__ bna,
                                              float* __restrict__ stats,
                                              unsigned short* __restrict__ resw2) {
    int g = blockIdx.x, tid = threadIdx.x;
    if (g < 24) {
        if (tid < 25) {
            int w = tid;
            float nb = 0.f, na = 0.f;
            for (int v = 0; v < 25; v++) {
                float e = emb[g*12 + hop[v*25 + w]];
                nb += e*e;
                float a = A[((size_t)g*25 + v)*25 + w];
                na += a*a;
            }
            nb = sqrtf(nb) + 1e-4f;
            na = sqrtf(na) + 1e-4f;
            for (int v = 0; v < 25; v++) {
                float e = emb[g*12 + hop[v*25 + w]];
                float a = A[((size_t)g*25 + v)*25 + w];
                bna[g*625 + v*25 + w] = e/nb + a/na;
            }
        }
    } else if (g == 24) {
#pragma unroll
        for (int i = 0; i < 4; i++) stats[i*256 + tid] = 0.f;
    } else {
        int base = (g - 25) * 4096 + tid * 16;
#pragma unroll
        for (int j = 0; j < 16; j++) resw2[base + j] = f2bf(res_w[base + j]);
    }
}

// K2+K3 merged. blocks [0,128): E2 build.  blocks [128,2176): x -> xb bf16 repack.
__global__ __launch_bounds__(256) void k_prep2x(const float* __restrict__ w_block,
                                                const float* __restrict__ bna,
                                                unsigned short* __restrict__ E2,
                                                const float* __restrict__ x,
                                                unsigned short* __restrict__ xb) {
    int bid = blockIdx.x, tid = threadIdx.x;
    if (bid < 128) {
        __shared__ float bl[3*625];
        __shared__ float wl[3*64];
        int half = bid & 1, og = (bid >> 1) & 7, h = bid >> 4;

        for (int i = tid; i < 1875; i += 256) {
            int k3 = i / 625, j = i - k3*625;
            bl[i] = bna[(k3*8 + h)*625 + j];
        }
        if (tid < 192) {
            int k3 = tid >> 6, o = (tid >> 4) & 3, c = tid & 15;
            wl[tid] = w_block[(k3*256 + h*32 + og*4 + o)*16 + c];
        }
        __syncthreads();

        unsigned short* dst = E2 + (size_t)(h*8 + og)*53248;
        int e0 = half * 26624;
        for (int e = e0 + tid; e < e0 + 26624; e += 256) {
            int kc = e >> 12;
            int n  = (e >> 5) & 127;
            int kk = e & 31;
            int k  = kc*32 + kk;
            int o  = n >> 5, w = n & 31;
            float val = 0.f;
            if (k < 400 && w < 25) {
                int c = k / 25, v = k - c*25;
                val = wl[0*64 + o*16 + c] * bl[0*625 + v*25 + w]
                    + wl[1*64 + o*16 + c] * bl[1*625 + v*25 + w]
                    + wl[2*64 + o*16 + c] * bl[2*625 + v*25 + w];
            }
            dst[e] = f2bf(val);
        }
    } else {
        int b = bid - 128;
        int n_ = b >> 7, t_ = b & 127;
        unsigned short* row = xb + (size_t)b * 3328;
        for (int idx = tid; idx < 3200; idx += 256) {
            int c = idx / 25, v = idx - c*25;
            float val = x[(((size_t)n_*128 + c)*128 + t_)*25 + v];
            row[(c >> 4)*416 + (c & 15)*25 + v] = f2bf(val);
        }
        if (tid < 128) row[(tid >> 4)*416 + 400 + (tid & 15)] = 0;
    }
}

// K4+K5 merged: blocks [0,1024) = main GEMM (gc), blocks [1024,1824) = residual GEMM.
// gc: 3-deep staging pipeline with COUNTED vmcnt (never 0 in steady state) + raw
// s_barrier. 3 LDS buffers x (A+B) = 48KB. Outputs in [n][oc][t][v] layout (= out).
__global__ __launch_bounds__(256) void k_mm(const unsigned short* __restrict__ xb,
                                            const unsigned short* __restrict__ E2,
                                            unsigned short* __restrict__ mainp,
                                            const float* __restrict__ x,
                                            const unsigned short* __restrict__ resw2,
                                            unsigned short* __restrict__ resp,
                                            float* __restrict__ stats) {
    // 3 buffers of 8192 shorts: [A 4096][B 4096] each
    __shared__ unsigned short lds[24576];
    int bid = blockIdx.x, tid = threadIdx.x;
    int lane = tid & 63, wave = tid >> 6;
    int wm = wave >> 1, wn = wave & 1;
    int lane15 = lane & 15, quad = lane >> 4;

    // inverse swizzle for linear gl_lds destinations (loop-invariant)
    int Lrow0 = wave*32 + (lane >> 2), Lq = lane & 3;
    int r0 = Lrow0 ^ ((Lrow0 >> 2) & 1), q0 = Lq ^ (r0 & 3);
    int Lrow1 = Lrow0 + 16;
    int r1 = Lrow1 ^ ((Lrow1 >> 2) & 1), q1 = Lq ^ (r1 & 3);

    const int adoff = wave*1024 + lane*8;   // per-lane dest offset within a half-buffer

    if (bid < 1024) {
        // h fastest -> bid%8==h -> same-h blocks share an XCD L2
        int h = bid & 7, og = (bid >> 3) & 7, mt = bid >> 6;

        const unsigned short* agA0 = xb + (size_t)(mt*128 + r0)*3328 + h*416 + q0*8;
        const unsigned short* agA1 = xb + (size_t)(mt*128 + r1)*3328 + h*416 + q1*8;
        const unsigned short* eb   = E2 + (size_t)(h*8 + og)*53248;
        const unsigned short* bgB0 = eb + r0*32 + q0*8;
        const unsigned short* bgB1 = eb + r1*32 + q1*8;

        f32x4 acc[4][4] = {};

        // prologue: stage batches 0,1,2 into bufs 0,1,2 (12 loads in flight)
#pragma unroll
        for (int p = 0; p < 3; p++) {
            int bo = p*8192;
            stage_pair(agA0 + p*32,           agA1 + p*32,           lds + bo + adoff);
            stage_pair(bgB0 + (size_t)p*4096, bgB1 + (size_t)p*4096, lds + bo + 4096 + adoff);
        }

        int bufo = 0;
        for (int kc = 0; kc < 13; kc++) {
            // counted wait: batch kc landed; batches kc+1,kc+2 stay in flight
            if (kc <= 10)      asm volatile("s_waitcnt vmcnt(8)" ::: "memory");
            else if (kc == 11) asm volatile("s_waitcnt vmcnt(4)" ::: "memory");
            else               asm volatile("s_waitcnt vmcnt(0)" ::: "memory");
            __builtin_amdgcn_s_barrier();        // publish buf kc to all waves

            const unsigned short* Ac = lds + bufo;
            const unsigned short* Bc = lds + bufo + 4096;
            short8 af[4], bq[4];
#pragma unroll
            for (int i = 0; i < 4; i++) {
                af[i] = *(const short8*)&Ac[swz_idx(wm*64 + i*16 + lane15, quad)];
                bq[i] = *(const short8*)&Bc[swz_idx(wn*64 + i*16 + lane15, quad)];
            }
            asm volatile("s_waitcnt lgkmcnt(0)" ::: "memory");  // frags in regs
            __builtin_amdgcn_sched_barrier(0);
            __builtin_amdgcn_s_barrier();        // all waves done reading buf kc

            if (kc <= 9) {                       // stage batch kc+3 into same buf
                stage_pair(agA0 + (kc+3)*32,            agA1 + (kc+3)*32,
                           lds + bufo + adoff);
                stage_pair(bgB0 + (size_t)(kc+3)*4096,  bgB1 + (size_t)(kc+3)*4096,
                           lds + bufo + 4096 + adoff);
            }
#pragma unroll
            for (int i = 0; i < 4; i++)
#pragma unroll
                for (int j = 0; j < 4; j++)
                    acc[i][j] = __builtin_amdgcn_mfma_f32_16x16x32_bf16(af[i], bq[j], acc[i][j], 0, 0, 0);

            bufo += 8192;
            if (bufo == 24576) bufo = 0;
        }

        // epilogue: n = wn*64 + j*16 + lane15 = o*32 + w; mainp layout [n][oc][t][w]
        float s1[2] = {0.f, 0.f}, s2[2] = {0.f, 0.f};
#pragma unroll
        for (int j = 0; j < 4; j++) {
            int w = (j & 1)*16 + lane15;
            int p = j >> 1;
            if (w < 25) {
                int oc = h*32 + og*4 + wn*2 + p;
#pragma unroll
                for (int i = 0; i < 4; i++) {
                    int tb = wm*64 + i*16 + quad*4;
#pragma unroll
                    for (int r = 0; r < 4; r++) {
                        float val = acc[i][j][r];
                        mainp[((size_t)(mt*256 + oc)*128 + tb + r)*25 + w] = f2bf(val);
                        s1[p] += val;
                        s2[p] = fmaf(val, val, s2[p]);
                    }
                }
            }
        }
#pragma unroll
        for (int p = 0; p < 2; p++) {
            float a = wave_sum(s1[p]);
            float b = wave_sum(s2[p]);
            if (lane == 0) {
                int oc = h*32 + og*4 + wn*2 + p;
                atomicAdd(&stats[oc], a);
                atomicAdd(&stats[256 + oc], b);
            }
        }
    } else {
        // residual GEMM: pair (mt, nt=0/1) at bids b2, b2+400 -> same XCD (400%8==0)
        int b2 = bid - 1024;
        int nt = (b2 >= 400) ? 1 : 0;
        int mt = b2 - nt*400;

        int n  = mt / 25;
        int off = (mt - n*25) * 128;
        const float* xb2 = x + (size_t)n*409600 + off;

        int c2 = tid >> 4, seg = tid & 15;   // c-pair (2c2,2c2+1), m = seg + 16j

        const unsigned short* rb0 = resw2 + (size_t)(nt*128 + r0)*128 + q0*8;
        const unsigned short* rb1 = resw2 + (size_t)(nt*128 + r1)*128 + q1*8;

        f32x4 acc[4][4] = {};

        for (int kc = 0; kc < 4; kc++) {
            // B stage first (latency overlaps the A pack below)
            stage_pair(rb0 + kc*32, rb1 + kc*32, lds + 4096 + adoff);
            const float* xc0 = xb2 + (size_t)(kc*32 + 2*c2)*3200;
            const float* xc1 = xc0 + 3200;
            int wbase = 2*(c2 & 3), qn = c2 >> 2;
#pragma unroll
            for (int j = 0; j < 8; j++) {
                int m = seg + 16*j;
                unsigned pk = (unsigned)f2bf(xc0[m]) | ((unsigned)f2bf(xc1[m]) << 16);
                *(unsigned*)&lds[swz_idx(m, qn) + wbase] = pk;
            }
            __syncthreads();

            short8 af[4], bq[4];
#pragma unroll
            for (int i = 0; i < 4; i++) {
                af[i] = *(const short8*)&lds[swz_idx(wm*64 + i*16 + lane15, quad)];
                bq[i] = *(const short8*)&lds[4096 + swz_idx(wn*64 + i*16 + lane15, quad)];
            }
#pragma unroll
            for (int i = 0; i < 4; i++)
#pragma unroll
                for (int j = 0; j < 4; j++)
                    acc[i][j] = __builtin_amdgcn_mfma_f32_16x16x32_bf16(af[i], bq[j], acc[i][j], 0, 0, 0);
            __syncthreads();
        }

#pragma unroll
        for (int j = 0; j < 4; j++) {
            int oc = nt*128 + wn*64 + j*16 + lane15;
            float s1 = 0.f, s2 = 0.f;
#pragma unroll
            for (int i = 0; i < 4; i++) {
                int m2b = mt*128 + wm*64 + i*16 + quad*4;
#pragma unroll
                for (int r = 0; r < 4; r++) {
                    float val = acc[i][j][r];
                    int m2e = m2b + r;
                    int b = m2e / 25, v = m2e - b*25;
                    int nn = b >> 7, t = b & 127;
                    resp[((size_t)(nn*256 + oc)*128 + t)*25 + v] = f2bf(val);
                    s1 += val;
                    s2 = fmaf(val, val, s2);
                }
            }
            s1 += __shfl_xor(s1, 16, 64); s1 += __shfl_xor(s1, 32, 64);
            s2 += __shfl_xor(s2, 16, 64); s2 += __shfl_xor(s2, 32, 64);
            if (quad == 0) {
                atomicAdd(&stats[512 + oc], s1);
                atomicAdd(&stats[768 + oc], s2);
            }
        }
    }
}

// K6: out = relu(BN1(main) + BN2(res)); mainp/resp layout == out layout, so this is
// a pure coalesced affine elementwise op. 1600 blocks x 256 thr x 4 chunks x 8 elems.
__global__ __launch_bounds__(256) void k_final(const float* __restrict__ bn_g,
                                               const float* __restrict__ bn_b,
                                               const float* __restrict__ rbn_g,
                                               const float* __restrict__ rbn_b,
                                               const float* __restrict__ stats,
                                               const unsigned short* __restrict__ mainp,
                                               const unsigned short* __restrict__ resp,
                                               float* __restrict__ out) {
    __shared__ float4 cf[8];
    int bid = blockIdx.x, tid = threadIdx.x;
    int base_row = (bid * 1024) / 400;       // (n,oc)-row of first chunk; <=3 rows/block span
    if (tid < 8) {
        int row = base_row + tid;
        if (row < 4096) {
            int oc = row & 255;
            const float inv = 1.f / NTV;
            float s1 = stats[oc],       s2 = stats[256 + oc];
            float r1v = stats[512 + oc], r2v = stats[768 + oc];
            float mm = s1*inv, vm = s2*inv - mm*mm;
            float mr = r1v*inv, vr = r2v*inv - mr*mr;
            float a1 = bn_g[oc]  * rsqrtf(vm + 1e-5f);
            float c1 = bn_b[oc]  - a1*mm;
            float a2 = rbn_g[oc] * rsqrtf(vr + 1e-5f);
            float c2 = rbn_b[oc] - a2*mr;
            cf[tid] = make_float4(a1, c1, a2, c2);
        }
    }
    __syncthreads();

    const uint4* m4 = (const uint4*)mainp;
    const uint4* r4 = (const uint4*)resp;
    float4* o4 = (float4*)out;
#pragma unroll
    for (int r = 0; r < 4; r++) {
        int chunk = bid*1024 + r*256 + tid;
        uint4 mu = m4[chunk];
        uint4 ru = r4[chunk];
        float4 C = cf[chunk/400 - base_row];
        float4 f0, f1;
        f0.x = fmaxf(fmaf(C.x, __uint_as_float(mu.x << 16),        C.y)
                   + fmaf(C.z, __uint_as_float(ru.x << 16),        C.w), 0.f);
        f0.y = fmaxf(fmaf(C.x, __uint_as_float(mu.x & 0xffff0000u), C.y)
                   + fmaf(C.z, __uint_as_float(ru.x & 0xffff0000u), C.w), 0.f);
        f0.z = fmaxf(fmaf(C.x, __uint_as_float(mu.y << 16),        C.y)
                   + fmaf(C.z, __uint_as_float(ru.y << 16),        C.w), 0.f);
        f0.w = fmaxf(fmaf(C.x, __uint_as_float(mu.y & 0xffff0000u), C.y)
                   + fmaf(C.z, __uint_as_float(ru.y & 0xffff0000u), C.w), 0.f);
        f1.x = fmaxf(fmaf(C.x, __uint_as_float(mu.z << 16),        C.y)
                   + fmaf(C.z, __uint_as_float(ru.z << 16),        C.w), 0.f);
        f1.y = fmaxf(fmaf(C.x, __uint_as_float(mu.z & 0xffff0000u), C.y)
                   + fmaf(C.z, __uint_as_float(ru.z & 0xffff0000u), C.w), 0.f);
        f1.z = fmaxf(fmaf(C.x, __uint_as_float(mu.w << 16),        C.y)
                   + fmaf(C.z, __uint_as_float(ru.w << 16),        C.w), 0.f);
        f1.w = fmaxf(fmaf(C.x, __uint_as_float(mu.w & 0xffff0000u), C.y)
                   + fmaf(C.z, __uint_as_float(ru.w & 0xffff0000u), C.w), 0.f);
        o4[chunk*2]     = f0;
        o4[chunk*2 + 1] = f1;
    }
}

extern "C" void kernel_launch(void* const* d_in, const int* in_sizes, int n_in,
                              void* d_out, int out_size, void* d_ws, size_t ws_size,
                              hipStream_t stream) {
    const float* x        = (const float*)d_in[0];
    const int*   hop      = (const int*)  d_in[1];
    const float* emb      = (const float*)d_in[2];
    const float* A        = (const float*)d_in[3];
    const float* w_block  = (const float*)d_in[4];
    // d_in[5] b_block, d_in[9] res_b: per-channel biases cancel under batchnorm.
    const float* bn_g     = (const float*)d_in[6];
    const float* bn_b     = (const float*)d_in[7];
    const float* res_w    = (const float*)d_in[8];
    const float* rbn_g    = (const float*)d_in[10];
    const float* rbn_b    = (const float*)d_in[11];
    float* out = (float*)d_out;

    char* ws = (char*)d_ws;
    float*          bna    = (float*)(ws + B_BNA);
    float*          stats  = (float*)(ws + B_STATS);
    unsigned short* resw2  = (unsigned short*)(ws + B_RESW2);
    unsigned short* E2     = (unsigned short*)(ws + B_E2);
    unsigned short* xb     = (unsigned short*)(ws + B_XB);
    unsigned short* mainp  = (unsigned short*)(ws + B_MAIN);
    unsigned short* resp   = (unsigned short*)(ws + B_RES);

    k_prep   <<<33,   256, 0, stream>>>(hop, emb, A, res_w, bna, stats, resw2);
    k_prep2x <<<2176, 256, 0, stream>>>(w_block, bna, E2, x, xb);
    k_mm     <<<1824, 256, 0, stream>>>(xb, E2, mainp, x, resw2, resp, stats);
    k_final  <<<1600, 256, 0, stream>>>(bn_g, bn_b, rbn_g, rbn_b, stats, mainp, resp, out);
}